// Round 1
// baseline (5959.806 us; speedup 1.0000x reference)
//
#include <hip/hip_runtime.h>
#include <hip/hip_bf16.h>

// Problem constants (match reference)
#define NN 100000
#define NE 1600000
#define NG 512
#define H  128

// ---------------------------------------------------------------------------
// degree: deg[dst] += 1 for each edge (self-loop handled as +1 in dinv pass)
__global__ __launch_bounds__(256) void degree_kernel(const int* __restrict__ dst,
                                                     float* __restrict__ deg, int E) {
    int e = blockIdx.x * 256 + threadIdx.x;
    if (e < E) atomicAdd(&deg[dst[e]], 1.0f);
}

__global__ __launch_bounds__(256) void dinv_kernel(float* __restrict__ deg, int n) {
    int i = blockIdx.x * 256 + threadIdx.x;
    if (i < n) deg[i] = rsqrtf(deg[i] + 1.0f);  // deg includes self-loop => >= 1
}

// ---------------------------------------------------------------------------
// C[n x 128] = A[n x 128] @ W[128 x 128]; 32 rows per block, 256 threads.
// K split in chunks of 64 staged in LDS (8KB x-tile + 32KB W-tile = 40KB).
__global__ __launch_bounds__(256) void gemm128(const float* __restrict__ A,
                                               const float* __restrict__ W,
                                               float* __restrict__ C) {
    __shared__ float xs[32][64];
    __shared__ float ws[64][128];
    const int tid = threadIdx.x;
    const int row0 = blockIdx.x * 32;
    const int tx = tid & 31;   // col group: cols 4*tx .. 4*tx+3
    const int ty = tid >> 5;   // row group: rows 4*ty .. 4*ty+3
    float acc[4][4] = {};

    for (int kc = 0; kc < 128; kc += 64) {
        // stage x chunk: 32 rows x 64 cols = 512 float4, 2 per thread
        #pragma unroll
        for (int i = tid; i < 32 * 16; i += 256) {
            int r = i >> 4, k4 = i & 15;
            ((float4*)xs[r])[k4] =
                ((const float4*)(A + (size_t)(row0 + r) * H + kc))[k4];
        }
        // stage W chunk: 64 rows x 128 cols = 2048 float4, 8 per thread
        #pragma unroll
        for (int i = tid; i < 64 * 32; i += 256) {
            int k = i >> 5, c4 = i & 31;
            ((float4*)ws[k])[c4] = ((const float4*)(W + (size_t)(kc + k) * H))[c4];
        }
        __syncthreads();
        #pragma unroll
        for (int k = 0; k < 64; ++k) {
            float4 wv = ((float4*)ws[k])[tx];
            float xv[4];
            #pragma unroll
            for (int r = 0; r < 4; ++r) xv[r] = xs[4 * ty + r][k];
            #pragma unroll
            for (int r = 0; r < 4; ++r) {
                acc[r][0] += xv[r] * wv.x;
                acc[r][1] += xv[r] * wv.y;
                acc[r][2] += xv[r] * wv.z;
                acc[r][3] += xv[r] * wv.w;
            }
        }
        __syncthreads();
    }
    #pragma unroll
    for (int r = 0; r < 4; ++r) {
        float4 v = make_float4(acc[r][0], acc[r][1], acc[r][2], acc[r][3]);
        ((float4*)(C + (size_t)(row0 + 4 * ty + r) * H))[tx] = v;
    }
}

// ---------------------------------------------------------------------------
// scatter: out[dst] += h[src] * dinv[src]*dinv[dst]; 32 threads per edge,
// each handles one float4 (4 scalar atomics).
__global__ __launch_bounds__(256) void scatter_kernel(const float* __restrict__ h,
                                                      const int* __restrict__ src,
                                                      const int* __restrict__ dst,
                                                      const float* __restrict__ dinv,
                                                      float* __restrict__ out, int E) {
    long long t = (long long)blockIdx.x * 256 + threadIdx.x;
    int e = (int)(t >> 5);
    if (e >= E) return;
    int j4 = (int)(t & 31);
    int s = src[e], d = dst[e];
    float norm = dinv[s] * dinv[d];
    float4 v = ((const float4*)(h + (size_t)s * H))[j4];
    float* o = out + (size_t)d * H + 4 * j4;
    atomicAdd(o + 0, v.x * norm);
    atomicAdd(o + 1, v.y * norm);
    atomicAdd(o + 2, v.z * norm);
    atomicAdd(o + 3, v.w * norm);
}

// ---------------------------------------------------------------------------
// finalize layer 1: out = relu(out + t*dinv^2 + b); elementwise float4
__global__ __launch_bounds__(256) void finalize1_kernel(float* __restrict__ out,
                                                        const float* __restrict__ t,
                                                        const float* __restrict__ dinv,
                                                        const float* __restrict__ b,
                                                        int n4) {
    int i = blockIdx.x * 256 + threadIdx.x;
    if (i >= n4) return;
    int row = i >> 5, c4 = i & 31;
    float di = dinv[row];
    float sl = di * di;
    float4 o = ((float4*)out)[i];
    float4 tv = ((const float4*)t)[i];
    float4 bv = ((const float4*)b)[c4];
    float4 r;
    r.x = fmaxf(o.x + tv.x * sl + bv.x, 0.0f);
    r.y = fmaxf(o.y + tv.y * sl + bv.y, 0.0f);
    r.z = fmaxf(o.z + tv.z * sl + bv.z, 0.0f);
    r.w = fmaxf(o.w + tv.w * sl + bv.w, 0.0f);
    ((float4*)out)[i] = r;
}

// ---------------------------------------------------------------------------
// finalize layer 2 fused with pooling head:
// v = relu(out2 + t2*dinv^2 + b2); s_node = dot(v, Wp); pool[batch] += s_node.
// One wave (64 lanes) per node, 4 nodes per 256-thread block.
__global__ __launch_bounds__(256) void finalize2_pool_kernel(
        const float* __restrict__ out2, const float* __restrict__ t2,
        const float* __restrict__ dinv, const float* __restrict__ b,
        const float* __restrict__ Wp, const int* __restrict__ batch,
        float* __restrict__ pool, float* __restrict__ cnt, int n) {
    int node = blockIdx.x * 4 + (threadIdx.x >> 6);
    int lane = threadIdx.x & 63;
    if (node >= n) return;
    float di = dinv[node];
    float sl = di * di;
    size_t base = (size_t)node * H;
    float s = 0.0f;
    #pragma unroll
    for (int jj = 0; jj < 2; ++jj) {
        int j = lane + 64 * jj;
        float v = out2[base + j] + t2[base + j] * sl + b[j];
        v = fmaxf(v, 0.0f);
        s += v * Wp[j];
    }
    #pragma unroll
    for (int off = 32; off > 0; off >>= 1) s += __shfl_down(s, off);
    if (lane == 0) {
        int g = batch[node];
        atomicAdd(&pool[g], s);
        atomicAdd(&cnt[g], 1.0f);
    }
}

// ---------------------------------------------------------------------------
__global__ __launch_bounds__(256) void final_out_kernel(const float* __restrict__ pool,
                                                        const float* __restrict__ cnt,
                                                        const float* __restrict__ bp,
                                                        float* __restrict__ out, int g) {
    int i = blockIdx.x * 256 + threadIdx.x;
    if (i < g) out[i] = pool[i] / fmaxf(cnt[i], 1.0f) + bp[0];
}

// ---------------------------------------------------------------------------
extern "C" void kernel_launch(void* const* d_in, const int* in_sizes, int n_in,
                              void* d_out, int out_size, void* d_ws, size_t ws_size,
                              hipStream_t stream) {
    const float* x     = (const float*)d_in[0];
    const int*   ei    = (const int*)d_in[1];   // [2, E]: src = ei[0:E], dst = ei[E:2E]
    const int*   batch = (const int*)d_in[2];
    const float* W1    = (const float*)d_in[3];
    const float* b1    = (const float*)d_in[4];
    const float* W2    = (const float*)d_in[5];
    const float* b2    = (const float*)d_in[6];
    const float* Wp    = (const float*)d_in[7];
    const float* bp    = (const float*)d_in[8];
    float* out = (float*)d_out;

    const int E = in_sizes[1] / 2;   // 1,600,000
    const int* src = ei;
    const int* dst = ei + E;

    // workspace layout
    const size_t BUF = (size_t)NN * H * sizeof(float);       // 51.2 MB
    char* ws = (char*)d_ws;
    float* bufA = (float*)(ws);                               // GEMM outputs t
    float* bufB = (float*)(ws + BUF);                         // scatter outputs
    float* dinv = (float*)(ws + 2 * BUF);                     // N floats
    size_t offP = 2 * BUF + ((NN * sizeof(float) + 255) / 256) * 256;
    float* pool = (float*)(ws + offP);                        // NG floats
    float* cnt  = (float*)(ws + offP + 2048);                 // NG floats

    // --- degrees ---
    hipMemsetAsync(dinv, 0, NN * sizeof(float), stream);
    hipMemsetAsync(ws + offP, 0, 4096, stream);               // pool + cnt
    degree_kernel<<<(E + 255) / 256, 256, 0, stream>>>(dst, dinv, E);
    dinv_kernel<<<(NN + 255) / 256, 256, 0, stream>>>(dinv, NN);

    // --- layer 1 ---
    gemm128<<<NN / 32, 256, 0, stream>>>(x, W1, bufA);
    hipMemsetAsync(bufB, 0, BUF, stream);
    {
        long long tot = (long long)E * 32;
        scatter_kernel<<<(unsigned)((tot + 255) / 256), 256, 0, stream>>>(
            bufA, src, dst, dinv, bufB, E);
    }
    finalize1_kernel<<<(NN * 32 + 255) / 256, 256, 0, stream>>>(bufB, bufA, dinv, b1,
                                                                NN * 32);

    // --- layer 2 ---
    gemm128<<<NN / 32, 256, 0, stream>>>(bufB, W2, bufA);
    hipMemsetAsync(bufB, 0, BUF, stream);
    {
        long long tot = (long long)E * 32;
        scatter_kernel<<<(unsigned)((tot + 255) / 256), 256, 0, stream>>>(
            bufA, src, dst, dinv, bufB, E);
    }
    finalize2_pool_kernel<<<(NN + 3) / 4, 256, 0, stream>>>(bufB, bufA, dinv, b2, Wp,
                                                            batch, pool, cnt, NN);

    // --- head ---
    final_out_kernel<<<(NG + 255) / 256, 256, 0, stream>>>(pool, cnt, bp, out, NG);
}

// Round 2
// 828.511 us; speedup vs baseline: 7.1934x; 7.1934x over previous
//
#include <hip/hip_runtime.h>
#include <hip/hip_bf16.h>

// Problem constants (match reference)
#define NN 100000
#define NG 512
#define H  128

// ---------------------------------------------------------------------------
// CSR build: histogram of dst
__global__ __launch_bounds__(256) void k_hist(const int* __restrict__ dst,
                                              int* __restrict__ deg, int E) {
    int e = blockIdx.x * 256 + threadIdx.x;
    if (e < E) atomicAdd(&deg[dst[e]], 1);
}

// per-block exclusive scan (256 elems), partial sums to bsum
__global__ __launch_bounds__(256) void k_scan_block(const int* __restrict__ deg,
                                                    int* __restrict__ rowptr,
                                                    int* __restrict__ bsum, int n) {
    __shared__ int s[256];
    int tid = threadIdx.x;
    int i = blockIdx.x * 256 + tid;
    int v = (i < n) ? deg[i] : 0;
    s[tid] = v;
    __syncthreads();
    #pragma unroll
    for (int off = 1; off < 256; off <<= 1) {
        int t = (tid >= off) ? s[tid - off] : 0;
        __syncthreads();
        s[tid] += t;
        __syncthreads();
    }
    if (i < n) rowptr[i] = s[tid] - v;            // exclusive within block
    if (tid == 255) bsum[blockIdx.x] = s[255];    // block total
}

// scan of block sums (NB <= 512), single block
__global__ __launch_bounds__(512) void k_scan_top(int* __restrict__ bsum, int nb) {
    __shared__ int s[512];
    int tid = threadIdx.x;
    int v = (tid < nb) ? bsum[tid] : 0;
    s[tid] = v;
    __syncthreads();
    #pragma unroll
    for (int off = 1; off < 512; off <<= 1) {
        int t = (tid >= off) ? s[tid - off] : 0;
        __syncthreads();
        s[tid] += t;
        __syncthreads();
    }
    if (tid < nb) bsum[tid] = s[tid] - v;         // exclusive
}

// finalize: rowptr += block offset; cursor = rowptr; dinv = rsqrt(deg+1)
__global__ __launch_bounds__(256) void k_scan_fin(int* __restrict__ rowptr,
                                                  const int* __restrict__ bsum,
                                                  const int* __restrict__ deg,
                                                  int* __restrict__ cursor,
                                                  float* __restrict__ dinv,
                                                  int n, int E) {
    int i = blockIdx.x * 256 + threadIdx.x;
    if (i >= n) return;
    int r = rowptr[i] + bsum[i >> 8];
    rowptr[i] = r;
    cursor[i] = r;
    dinv[i] = rsqrtf((float)deg[i] + 1.0f);       // +1 self-loop; always > 0
    if (i == 0) rowptr[n] = E;
}

// fill CSR column array
__global__ __launch_bounds__(256) void k_fill(const int* __restrict__ src,
                                              const int* __restrict__ dst,
                                              int* __restrict__ cursor,
                                              int* __restrict__ col, int E) {
    int e = blockIdx.x * 256 + threadIdx.x;
    if (e >= E) return;
    int d = dst[e];
    int pos = atomicAdd(&cursor[d], 1);
    col[pos] = src[e];
}

// ---------------------------------------------------------------------------
// C[n x 128] = (A[n x 128] @ W[128 x 128]) * scale[row]; 32 rows/block.
__global__ __launch_bounds__(256) void gemm128(const float* __restrict__ A,
                                               const float* __restrict__ W,
                                               const float* __restrict__ scale,
                                               float* __restrict__ C) {
    __shared__ float xs[32][64];
    __shared__ float ws[64][128];
    const int tid = threadIdx.x;
    const int row0 = blockIdx.x * 32;
    const int tx = tid & 31;   // col group: cols 4*tx .. 4*tx+3
    const int ty = tid >> 5;   // row group: rows 4*ty .. 4*ty+3
    float acc[4][4] = {};

    for (int kc = 0; kc < 128; kc += 64) {
        #pragma unroll
        for (int i = tid; i < 32 * 16; i += 256) {
            int r = i >> 4, k4 = i & 15;
            ((float4*)xs[r])[k4] =
                ((const float4*)(A + (size_t)(row0 + r) * H + kc))[k4];
        }
        #pragma unroll
        for (int i = tid; i < 64 * 32; i += 256) {
            int k = i >> 5, c4 = i & 31;
            ((float4*)ws[k])[c4] = ((const float4*)(W + (size_t)(kc + k) * H))[c4];
        }
        __syncthreads();
        #pragma unroll
        for (int k = 0; k < 64; ++k) {
            float4 wv = ((float4*)ws[k])[tx];
            float xv[4];
            #pragma unroll
            for (int r = 0; r < 4; ++r) xv[r] = xs[4 * ty + r][k];
            #pragma unroll
            for (int r = 0; r < 4; ++r) {
                acc[r][0] += xv[r] * wv.x;
                acc[r][1] += xv[r] * wv.y;
                acc[r][2] += xv[r] * wv.z;
                acc[r][3] += xv[r] * wv.w;
            }
        }
        __syncthreads();
    }
    #pragma unroll
    for (int r = 0; r < 4; ++r) {
        int row = row0 + 4 * ty + r;
        float sc = scale[row];
        float4 v = make_float4(acc[r][0] * sc, acc[r][1] * sc,
                               acc[r][2] * sc, acc[r][3] * sc);
        ((float4*)(C + (size_t)row * H))[tx] = v;
    }
}

// ---------------------------------------------------------------------------
// gather layer 1: out[n] = relu(dinv[n]*(tS[n] + sum_{e in-edges} tS[col[e]]) + b)
// One wave per node, lane owns 2 features (float2). 4 nodes per 256-thread block.
__global__ __launch_bounds__(256) void k_gather1(const float* __restrict__ tS,
                                                 const int* __restrict__ rowptr,
                                                 const int* __restrict__ col,
                                                 const float* __restrict__ dinv,
                                                 const float* __restrict__ b,
                                                 float* __restrict__ out, int n) {
    int node = blockIdx.x * 4 + (threadIdx.x >> 6);
    int lane = threadIdx.x & 63;
    if (node >= n) return;
    const float2* t2 = (const float2*)tS;
    size_t base = (size_t)node * 64;
    float2 v = t2[base + lane];               // self-loop term
    float a0x = v.x, a0y = v.y, a1x = 0.f, a1y = 0.f;
    int e = rowptr[node], end = rowptr[node + 1];
    for (; e + 2 <= end; e += 2) {
        int s0 = col[e], s1 = col[e + 1];
        float2 v0 = t2[(size_t)s0 * 64 + lane];
        float2 v1 = t2[(size_t)s1 * 64 + lane];
        a0x += v0.x; a0y += v0.y;
        a1x += v1.x; a1y += v1.y;
    }
    if (e < end) {
        int s0 = col[e];
        float2 v0 = t2[(size_t)s0 * 64 + lane];
        a0x += v0.x; a0y += v0.y;
    }
    float dn = dinv[node];
    float2 bb = ((const float2*)b)[lane];
    float2 r;
    r.x = fmaxf(dn * (a0x + a1x) + bb.x, 0.0f);
    r.y = fmaxf(dn * (a0y + a1y) + bb.y, 0.0f);
    ((float2*)out)[base + lane] = r;
}

// gather layer 2 fused with pool head: v = relu(...); pool[batch[n]] += dot(v, Wp)
__global__ __launch_bounds__(256) void k_gather2(const float* __restrict__ tS,
                                                 const int* __restrict__ rowptr,
                                                 const int* __restrict__ col,
                                                 const float* __restrict__ dinv,
                                                 const float* __restrict__ b,
                                                 const float* __restrict__ Wp,
                                                 const int* __restrict__ batch,
                                                 float* __restrict__ pool,
                                                 float* __restrict__ cnt, int n) {
    int node = blockIdx.x * 4 + (threadIdx.x >> 6);
    int lane = threadIdx.x & 63;
    if (node >= n) return;
    const float2* t2 = (const float2*)tS;
    size_t base = (size_t)node * 64;
    float2 v = t2[base + lane];
    float a0x = v.x, a0y = v.y, a1x = 0.f, a1y = 0.f;
    int e = rowptr[node], end = rowptr[node + 1];
    for (; e + 2 <= end; e += 2) {
        int s0 = col[e], s1 = col[e + 1];
        float2 v0 = t2[(size_t)s0 * 64 + lane];
        float2 v1 = t2[(size_t)s1 * 64 + lane];
        a0x += v0.x; a0y += v0.y;
        a1x += v1.x; a1y += v1.y;
    }
    if (e < end) {
        int s0 = col[e];
        float2 v0 = t2[(size_t)s0 * 64 + lane];
        a0x += v0.x; a0y += v0.y;
    }
    float dn = dinv[node];
    float2 bb = ((const float2*)b)[lane];
    float2 wp = ((const float2*)Wp)[lane];
    float s = fmaxf(dn * (a0x + a1x) + bb.x, 0.0f) * wp.x +
              fmaxf(dn * (a0y + a1y) + bb.y, 0.0f) * wp.y;
    #pragma unroll
    for (int off = 32; off > 0; off >>= 1) s += __shfl_down(s, off);
    if (lane == 0) {
        int g = batch[node];
        atomicAdd(&pool[g], s);
        atomicAdd(&cnt[g], 1.0f);
    }
}

// ---------------------------------------------------------------------------
__global__ __launch_bounds__(256) void final_out_kernel(const float* __restrict__ pool,
                                                        const float* __restrict__ cnt,
                                                        const float* __restrict__ bp,
                                                        float* __restrict__ out, int g) {
    int i = blockIdx.x * 256 + threadIdx.x;
    if (i < g) out[i] = pool[i] / fmaxf(cnt[i], 1.0f) + bp[0];
}

// ---------------------------------------------------------------------------
extern "C" void kernel_launch(void* const* d_in, const int* in_sizes, int n_in,
                              void* d_out, int out_size, void* d_ws, size_t ws_size,
                              hipStream_t stream) {
    const float* x     = (const float*)d_in[0];
    const int*   ei    = (const int*)d_in[1];   // [2, E]: src = ei[0:E], dst = ei[E:2E]
    const int*   batch = (const int*)d_in[2];
    const float* W1    = (const float*)d_in[3];
    const float* b1    = (const float*)d_in[4];
    const float* W2    = (const float*)d_in[5];
    const float* b2    = (const float*)d_in[6];
    const float* Wp    = (const float*)d_in[7];
    const float* bp    = (const float*)d_in[8];
    float* out = (float*)d_out;

    const int E = in_sizes[1] / 2;   // 1,600,000
    const int* src = ei;
    const int* dst = ei + E;

    // workspace layout (aligned chunks)
    const size_t BUF = (size_t)NN * H * sizeof(float);       // 51.2 MB
    const size_t NI  = 401408;                                // >= (NN+1)*4, 4KB-mult
    char* ws = (char*)d_ws;
    size_t off = 0;
    float* bufA   = (float*)(ws + off); off += BUF;          // GEMM outputs tS
    float* bufB   = (float*)(ws + off); off += BUF;          // gather outputs h
    int*   deg    = (int*)  (ws + off); off += NI;
    int*   rowptr = (int*)  (ws + off); off += NI;
    int*   cursor = (int*)  (ws + off); off += NI;
    float* dinv   = (float*)(ws + off); off += NI;
    int*   col    = (int*)  (ws + off); off += ((size_t)E * 4 + 4095) / 4096 * 4096;
    int*   bsum   = (int*)  (ws + off); off += 4096;
    float* pool   = (float*)(ws + off); off += 2048;
    float* cnt    = (float*)(ws + off); off += 2048;

    const int NB = (NN + 255) / 256;   // 391 scan blocks

    // --- CSR build + degree norm ---
    hipMemsetAsync(deg, 0, NN * sizeof(int), stream);
    hipMemsetAsync(pool, 0, 4096, stream);                   // pool + cnt
    k_hist<<<(E + 255) / 256, 256, 0, stream>>>(dst, deg, E);
    k_scan_block<<<NB, 256, 0, stream>>>(deg, rowptr, bsum, NN);
    k_scan_top<<<1, 512, 0, stream>>>(bsum, NB);
    k_scan_fin<<<NB, 256, 0, stream>>>(rowptr, bsum, deg, cursor, dinv, NN, E);
    k_fill<<<(E + 255) / 256, 256, 0, stream>>>(src, dst, cursor, col, E);

    // --- layer 1 ---
    gemm128<<<NN / 32, 256, 0, stream>>>(x, W1, dinv, bufA);
    k_gather1<<<(NN + 3) / 4, 256, 0, stream>>>(bufA, rowptr, col, dinv, b1, bufB, NN);

    // --- layer 2 ---
    gemm128<<<NN / 32, 256, 0, stream>>>(bufB, W2, dinv, bufA);
    k_gather2<<<(NN + 3) / 4, 256, 0, stream>>>(bufA, rowptr, col, dinv, b2, Wp,
                                                batch, pool, cnt, NN);

    // --- head ---
    final_out_kernel<<<(NG + 255) / 256, 256, 0, stream>>>(pool, cnt, bp, out, NG);
}

// Round 3
// 784.098 us; speedup vs baseline: 7.6008x; 1.0566x over previous
//
#include <hip/hip_runtime.h>
#include <hip/hip_bf16.h>

// Problem constants (match reference)
#define NN 100000
#define NG 512
#define H  128

// ---------------------------------------------------------------------------
// CSR build: histogram of dst
__global__ __launch_bounds__(256) void k_hist(const int* __restrict__ dst,
                                              int* __restrict__ deg, int E) {
    int e = blockIdx.x * 256 + threadIdx.x;
    if (e < E) atomicAdd(&deg[dst[e]], 1);
}

// per-block exclusive scan (256 elems), partial sums to bsum
__global__ __launch_bounds__(256) void k_scan_block(const int* __restrict__ deg,
                                                    int* __restrict__ rowptr,
                                                    int* __restrict__ bsum, int n) {
    __shared__ int s[256];
    int tid = threadIdx.x;
    int i = blockIdx.x * 256 + tid;
    int v = (i < n) ? deg[i] : 0;
    s[tid] = v;
    __syncthreads();
    #pragma unroll
    for (int off = 1; off < 256; off <<= 1) {
        int t = (tid >= off) ? s[tid - off] : 0;
        __syncthreads();
        s[tid] += t;
        __syncthreads();
    }
    if (i < n) rowptr[i] = s[tid] - v;            // exclusive within block
    if (tid == 255) bsum[blockIdx.x] = s[255];    // block total
}

// scan of block sums (NB <= 512), single block
__global__ __launch_bounds__(512) void k_scan_top(int* __restrict__ bsum, int nb) {
    __shared__ int s[512];
    int tid = threadIdx.x;
    int v = (tid < nb) ? bsum[tid] : 0;
    s[tid] = v;
    __syncthreads();
    #pragma unroll
    for (int off = 1; off < 512; off <<= 1) {
        int t = (tid >= off) ? s[tid - off] : 0;
        __syncthreads();
        s[tid] += t;
        __syncthreads();
    }
    if (tid < nb) bsum[tid] = s[tid] - v;         // exclusive
}

// finalize: rowptr += block offset; cursor = rowptr; dinv = rsqrt(deg+1)
__global__ __launch_bounds__(256) void k_scan_fin(int* __restrict__ rowptr,
                                                  const int* __restrict__ bsum,
                                                  const int* __restrict__ deg,
                                                  int* __restrict__ cursor,
                                                  float* __restrict__ dinv,
                                                  int n, int E) {
    int i = blockIdx.x * 256 + threadIdx.x;
    if (i >= n) return;
    int r = rowptr[i] + bsum[i >> 8];
    rowptr[i] = r;
    cursor[i] = r;
    dinv[i] = rsqrtf((float)deg[i] + 1.0f);       // +1 self-loop; always > 0
    if (i == 0) rowptr[n] = E;
}

// fill CSR column array
__global__ __launch_bounds__(256) void k_fill(const int* __restrict__ src,
                                              const int* __restrict__ dst,
                                              int* __restrict__ cursor,
                                              int* __restrict__ col, int E) {
    int e = blockIdx.x * 256 + threadIdx.x;
    if (e >= E) return;
    int d = dst[e];
    int pos = atomicAdd(&cursor[d], 1);
    col[pos] = src[e];
}

// ---------------------------------------------------------------------------
// C[n x 128] = (A[n x 128] @ W[128 x 128]) * scale[row]; 32 rows/block.
__global__ __launch_bounds__(256) void gemm128(const float* __restrict__ A,
                                               const float* __restrict__ W,
                                               const float* __restrict__ scale,
                                               float* __restrict__ C) {
    __shared__ float xs[32][64];
    __shared__ float ws[64][128];
    const int tid = threadIdx.x;
    const int row0 = blockIdx.x * 32;
    const int tx = tid & 31;   // col group: cols 4*tx .. 4*tx+3
    const int ty = tid >> 5;   // row group: rows 4*ty .. 4*ty+3
    float acc[4][4] = {};

    for (int kc = 0; kc < 128; kc += 64) {
        #pragma unroll
        for (int i = tid; i < 32 * 16; i += 256) {
            int r = i >> 4, k4 = i & 15;
            ((float4*)xs[r])[k4] =
                ((const float4*)(A + (size_t)(row0 + r) * H + kc))[k4];
        }
        #pragma unroll
        for (int i = tid; i < 64 * 32; i += 256) {
            int k = i >> 5, c4 = i & 31;
            ((float4*)ws[k])[c4] = ((const float4*)(W + (size_t)(kc + k) * H))[c4];
        }
        __syncthreads();
        #pragma unroll
        for (int k = 0; k < 64; ++k) {
            float4 wv = ((float4*)ws[k])[tx];
            float xv[4];
            #pragma unroll
            for (int r = 0; r < 4; ++r) xv[r] = xs[4 * ty + r][k];
            #pragma unroll
            for (int r = 0; r < 4; ++r) {
                acc[r][0] += xv[r] * wv.x;
                acc[r][1] += xv[r] * wv.y;
                acc[r][2] += xv[r] * wv.z;
                acc[r][3] += xv[r] * wv.w;
            }
        }
        __syncthreads();
    }
    #pragma unroll
    for (int r = 0; r < 4; ++r) {
        int row = row0 + 4 * ty + r;
        float sc = scale[row];
        float4 v = make_float4(acc[r][0] * sc, acc[r][1] * sc,
                               acc[r][2] * sc, acc[r][3] * sc);
        ((float4*)(C + (size_t)row * H))[tx] = v;
    }
}

// ---------------------------------------------------------------------------
// Gather core: one wave per node. Lane l holds float4 (features 4*(l&31)..).
// Half-wave 0 covers even edge slots, half-wave 1 odd slots => each 64-lane
// load instruction fetches TWO 512B rows. col indices are bulk-loaded into a
// lane register (64 at a time) and broadcast via __shfl (no mem dependency).
// Returns per-lane float4 = self + sum of neighbor rows (full sum in all
// lanes after the xor-32 combine).
__device__ __forceinline__ float4 gather_rows(const float4* __restrict__ t4,
                                              const int* __restrict__ col,
                                              int node, int e0, int end) {
    const int lane = threadIdx.x & 63;
    const int half = lane >> 5;
    const int l32 = lane & 31;
    float4 a0 = make_float4(0.f, 0.f, 0.f, 0.f);
    float4 a1 = make_float4(0.f, 0.f, 0.f, 0.f);
    if (half == 0) a0 = t4[(size_t)node * 32 + l32];   // self-loop row

    for (int base = e0; base < end; base += 64) {
        int ce = base + lane;
        int cidx = (ce < end) ? col[ce] : 0;
        int m = min(64, end - base);
        int g4 = m >> 2;
        #pragma unroll 2
        for (int g = 0; g < g4; ++g) {
            int s0 = __shfl(cidx, 4 * g + half);
            int s1 = __shfl(cidx, 4 * g + 2 + half);
            float4 v0 = t4[(size_t)s0 * 32 + l32];
            float4 v1 = t4[(size_t)s1 * 32 + l32];
            a0.x += v0.x; a0.y += v0.y; a0.z += v0.z; a0.w += v0.w;
            a1.x += v1.x; a1.y += v1.y; a1.z += v1.z; a1.w += v1.w;
        }
        int t0 = 4 * g4 + half;
        if (t0 < m) {
            int s = __shfl(cidx, t0);
            float4 v = t4[(size_t)s * 32 + l32];
            a0.x += v.x; a0.y += v.y; a0.z += v.z; a0.w += v.w;
        }
        int t1 = t0 + 2;
        if (t1 < m) {
            int s = __shfl(cidx, t1);
            float4 v = t4[(size_t)s * 32 + l32];
            a1.x += v.x; a1.y += v.y; a1.z += v.z; a1.w += v.w;
        }
    }
    float4 a;
    a.x = a0.x + a1.x; a.y = a0.y + a1.y;
    a.z = a0.z + a1.z; a.w = a0.w + a1.w;
    // combine the two halves: lanes l and l^32 hold partial sums of the same
    // 4 features
    a.x += __shfl_xor(a.x, 32);
    a.y += __shfl_xor(a.y, 32);
    a.z += __shfl_xor(a.z, 32);
    a.w += __shfl_xor(a.w, 32);
    return a;
}

// gather layer 1: out[n] = relu(dinv[n]*(tS[n] + sum in-edges) + b)
__global__ __launch_bounds__(256) void k_gather1(const float* __restrict__ tS,
                                                 const int* __restrict__ rowptr,
                                                 const int* __restrict__ col,
                                                 const float* __restrict__ dinv,
                                                 const float* __restrict__ b,
                                                 float* __restrict__ out, int n) {
    int node = blockIdx.x * 4 + (threadIdx.x >> 6);
    int lane = threadIdx.x & 63;
    int l32 = lane & 31;
    if (node >= n) return;
    int e0 = rowptr[node], end = rowptr[node + 1];
    float4 a = gather_rows((const float4*)tS, col, node, e0, end);
    if (lane < 32) {
        float dn = dinv[node];
        float4 bb = ((const float4*)b)[l32];
        float4 r;
        r.x = fmaxf(dn * a.x + bb.x, 0.0f);
        r.y = fmaxf(dn * a.y + bb.y, 0.0f);
        r.z = fmaxf(dn * a.z + bb.z, 0.0f);
        r.w = fmaxf(dn * a.w + bb.w, 0.0f);
        ((float4*)out)[(size_t)node * 32 + l32] = r;
    }
}

// gather layer 2 fused with pool head: v = relu(...); pool[batch[n]] += dot(v, Wp)
__global__ __launch_bounds__(256) void k_gather2(const float* __restrict__ tS,
                                                 const int* __restrict__ rowptr,
                                                 const int* __restrict__ col,
                                                 const float* __restrict__ dinv,
                                                 const float* __restrict__ b,
                                                 const float* __restrict__ Wp,
                                                 const int* __restrict__ batch,
                                                 float* __restrict__ pool,
                                                 float* __restrict__ cnt, int n) {
    int node = blockIdx.x * 4 + (threadIdx.x >> 6);
    int lane = threadIdx.x & 63;
    int l32 = lane & 31;
    if (node >= n) return;
    int e0 = rowptr[node], end = rowptr[node + 1];
    float4 a = gather_rows((const float4*)tS, col, node, e0, end);
    // both halves compute identical partials (a identical, l32 mirrors)
    float dn = dinv[node];
    float4 bb = ((const float4*)b)[l32];
    float4 wp = ((const float4*)Wp)[l32];
    float s = fmaxf(dn * a.x + bb.x, 0.0f) * wp.x +
              fmaxf(dn * a.y + bb.y, 0.0f) * wp.y +
              fmaxf(dn * a.z + bb.z, 0.0f) * wp.z +
              fmaxf(dn * a.w + bb.w, 0.0f) * wp.w;
    // reduce across lanes 0..31 (halves identical): xor masks 1..16
    s += __shfl_xor(s, 1);
    s += __shfl_xor(s, 2);
    s += __shfl_xor(s, 4);
    s += __shfl_xor(s, 8);
    s += __shfl_xor(s, 16);
    if (lane == 0) {
        int g = batch[node];
        atomicAdd(&pool[g], s);
        atomicAdd(&cnt[g], 1.0f);
    }
}

// ---------------------------------------------------------------------------
__global__ __launch_bounds__(256) void final_out_kernel(const float* __restrict__ pool,
                                                        const float* __restrict__ cnt,
                                                        const float* __restrict__ bp,
                                                        float* __restrict__ out, int g) {
    int i = blockIdx.x * 256 + threadIdx.x;
    if (i < g) out[i] = pool[i] / fmaxf(cnt[i], 1.0f) + bp[0];
}

// ---------------------------------------------------------------------------
extern "C" void kernel_launch(void* const* d_in, const int* in_sizes, int n_in,
                              void* d_out, int out_size, void* d_ws, size_t ws_size,
                              hipStream_t stream) {
    const float* x     = (const float*)d_in[0];
    const int*   ei    = (const int*)d_in[1];   // [2, E]: src = ei[0:E], dst = ei[E:2E]
    const int*   batch = (const int*)d_in[2];
    const float* W1    = (const float*)d_in[3];
    const float* b1    = (const float*)d_in[4];
    const float* W2    = (const float*)d_in[5];
    const float* b2    = (const float*)d_in[6];
    const float* Wp    = (const float*)d_in[7];
    const float* bp    = (const float*)d_in[8];
    float* out = (float*)d_out;

    const int E = in_sizes[1] / 2;   // 1,600,000
    const int* src = ei;
    const int* dst = ei + E;

    // workspace layout (aligned chunks)
    const size_t BUF = (size_t)NN * H * sizeof(float);       // 51.2 MB
    const size_t NI  = 401408;                                // >= (NN+1)*4, 4KB-mult
    char* ws = (char*)d_ws;
    size_t off = 0;
    float* bufA   = (float*)(ws + off); off += BUF;          // GEMM outputs tS
    float* bufB   = (float*)(ws + off); off += BUF;          // gather outputs h
    int*   deg    = (int*)  (ws + off); off += NI;
    int*   rowptr = (int*)  (ws + off); off += NI;
    int*   cursor = (int*)  (ws + off); off += NI;
    float* dinv   = (float*)(ws + off); off += NI;
    int*   col    = (int*)  (ws + off); off += ((size_t)E * 4 + 4095) / 4096 * 4096;
    int*   bsum   = (int*)  (ws + off); off += 4096;
    float* pool   = (float*)(ws + off); off += 2048;
    float* cnt    = (float*)(ws + off); off += 2048;

    const int NB = (NN + 255) / 256;   // 391 scan blocks

    // --- CSR build + degree norm ---
    hipMemsetAsync(deg, 0, NN * sizeof(int), stream);
    hipMemsetAsync(pool, 0, 4096, stream);                   // pool + cnt
    k_hist<<<(E + 255) / 256, 256, 0, stream>>>(dst, deg, E);
    k_scan_block<<<NB, 256, 0, stream>>>(deg, rowptr, bsum, NN);
    k_scan_top<<<1, 512, 0, stream>>>(bsum, NB);
    k_scan_fin<<<NB, 256, 0, stream>>>(rowptr, bsum, deg, cursor, dinv, NN, E);
    k_fill<<<(E + 255) / 256, 256, 0, stream>>>(src, dst, cursor, col, E);

    // --- layer 1 ---
    gemm128<<<NN / 32, 256, 0, stream>>>(x, W1, dinv, bufA);
    k_gather1<<<(NN + 3) / 4, 256, 0, stream>>>(bufA, rowptr, col, dinv, b1, bufB, NN);

    // --- layer 2 ---
    gemm128<<<NN / 32, 256, 0, stream>>>(bufB, W2, dinv, bufA);
    k_gather2<<<(NN + 3) / 4, 256, 0, stream>>>(bufA, rowptr, col, dinv, b2, Wp,
                                                batch, pool, cnt, NN);

    // --- head ---
    final_out_kernel<<<(NG + 255) / 256, 256, 0, stream>>>(pool, cnt, bp, out, NG);
}

// Round 4
// 728.965 us; speedup vs baseline: 8.1757x; 1.0756x over previous
//
#include <hip/hip_runtime.h>
#include <hip/hip_bf16.h>

// Problem constants (match reference)
#define NN 100000
#define NG 512
#define H  128

typedef _Float16 half8 __attribute__((ext_vector_type(8)));
typedef _Float16 half4v __attribute__((ext_vector_type(4)));

// ---------------------------------------------------------------------------
// CSR build: histogram of dst
__global__ __launch_bounds__(256) void k_hist(const int* __restrict__ dst,
                                              int* __restrict__ deg, int E) {
    int e = blockIdx.x * 256 + threadIdx.x;
    if (e < E) atomicAdd(&deg[dst[e]], 1);
}

// per-block exclusive scan (256 elems), partial sums to bsum
__global__ __launch_bounds__(256) void k_scan_block(const int* __restrict__ deg,
                                                    int* __restrict__ rowptr,
                                                    int* __restrict__ bsum, int n) {
    __shared__ int s[256];
    int tid = threadIdx.x;
    int i = blockIdx.x * 256 + tid;
    int v = (i < n) ? deg[i] : 0;
    s[tid] = v;
    __syncthreads();
    #pragma unroll
    for (int off = 1; off < 256; off <<= 1) {
        int t = (tid >= off) ? s[tid - off] : 0;
        __syncthreads();
        s[tid] += t;
        __syncthreads();
    }
    if (i < n) rowptr[i] = s[tid] - v;            // exclusive within block
    if (tid == 255) bsum[blockIdx.x] = s[255];    // block total
}

// scan of block sums (NB <= 512), single block
__global__ __launch_bounds__(512) void k_scan_top(int* __restrict__ bsum, int nb) {
    __shared__ int s[512];
    int tid = threadIdx.x;
    int v = (tid < nb) ? bsum[tid] : 0;
    s[tid] = v;
    __syncthreads();
    #pragma unroll
    for (int off = 1; off < 512; off <<= 1) {
        int t = (tid >= off) ? s[tid - off] : 0;
        __syncthreads();
        s[tid] += t;
        __syncthreads();
    }
    if (tid < nb) bsum[tid] = s[tid] - v;         // exclusive
}

// finalize: rowptr += block offset; cursor = rowptr; dinv = rsqrt(deg+1)
__global__ __launch_bounds__(256) void k_scan_fin(int* __restrict__ rowptr,
                                                  const int* __restrict__ bsum,
                                                  const int* __restrict__ deg,
                                                  int* __restrict__ cursor,
                                                  float* __restrict__ dinv,
                                                  int n, int E) {
    int i = blockIdx.x * 256 + threadIdx.x;
    if (i >= n) return;
    int r = rowptr[i] + bsum[i >> 8];
    rowptr[i] = r;
    cursor[i] = r;
    dinv[i] = rsqrtf((float)deg[i] + 1.0f);       // +1 self-loop; always > 0
    if (i == 0) rowptr[n] = E;
}

// fill CSR column array
__global__ __launch_bounds__(256) void k_fill(const int* __restrict__ src,
                                              const int* __restrict__ dst,
                                              int* __restrict__ cursor,
                                              int* __restrict__ col, int E) {
    int e = blockIdx.x * 256 + threadIdx.x;
    if (e >= E) return;
    int d = dst[e];
    int pos = atomicAdd(&cursor[d], 1);
    col[pos] = src[e];
}

// ---------------------------------------------------------------------------
// C_h[n x 128] (fp16) = (A[n x 128] @ W[128 x 128]) * scale[row]; 32 rows/block.
__global__ __launch_bounds__(256) void gemm128h(const float* __restrict__ A,
                                                const float* __restrict__ W,
                                                const float* __restrict__ scale,
                                                _Float16* __restrict__ C) {
    __shared__ float xs[32][64];
    __shared__ float ws[64][128];
    const int tid = threadIdx.x;
    const int row0 = blockIdx.x * 32;
    const int tx = tid & 31;   // col group: cols 4*tx .. 4*tx+3
    const int ty = tid >> 5;   // row group: rows 4*ty .. 4*ty+3
    float acc[4][4] = {};

    for (int kc = 0; kc < 128; kc += 64) {
        #pragma unroll
        for (int i = tid; i < 32 * 16; i += 256) {
            int r = i >> 4, k4 = i & 15;
            ((float4*)xs[r])[k4] =
                ((const float4*)(A + (size_t)(row0 + r) * H + kc))[k4];
        }
        #pragma unroll
        for (int i = tid; i < 64 * 32; i += 256) {
            int k = i >> 5, c4 = i & 31;
            ((float4*)ws[k])[c4] = ((const float4*)(W + (size_t)(kc + k) * H))[c4];
        }
        __syncthreads();
        #pragma unroll
        for (int k = 0; k < 64; ++k) {
            float4 wv = ((float4*)ws[k])[tx];
            float xv[4];
            #pragma unroll
            for (int r = 0; r < 4; ++r) xv[r] = xs[4 * ty + r][k];
            #pragma unroll
            for (int r = 0; r < 4; ++r) {
                acc[r][0] += xv[r] * wv.x;
                acc[r][1] += xv[r] * wv.y;
                acc[r][2] += xv[r] * wv.z;
                acc[r][3] += xv[r] * wv.w;
            }
        }
        __syncthreads();
    }
    #pragma unroll
    for (int r = 0; r < 4; ++r) {
        int row = row0 + 4 * ty + r;
        float sc = scale[row];
        half4v v;
        v[0] = (_Float16)(acc[r][0] * sc);
        v[1] = (_Float16)(acc[r][1] * sc);
        v[2] = (_Float16)(acc[r][2] * sc);
        v[3] = (_Float16)(acc[r][3] * sc);
        ((half4v*)(C + (size_t)row * H))[tx] = v;
    }
}

// ---------------------------------------------------------------------------
// Gather core, fp16 rows (256B). One wave per node. Quarter-wave q handles
// edge slot 4g+q; lane loads 16B (8 halves) of the row => one 64-lane load
// fetches FOUR rows. col indices bulk-loaded 64 at a time, broadcast by shfl.
// Accumulation fp32. After the xor-16/32 combine all lanes hold the full sum
// for features l16*8 .. l16*8+7.
__device__ __forceinline__ void gather_rows_h(const half8* __restrict__ t8,
                                              const int* __restrict__ col,
                                              int node, int e0, int end,
                                              float acc[8]) {
    const int lane = threadIdx.x & 63;
    const int q = lane >> 4;
    const int l16 = lane & 15;
    float a0[8] = {}, a1[8] = {};
    if (q == 0) {                                   // self-loop row
        half8 v = t8[(size_t)node * 16 + l16];
        #pragma unroll
        for (int i = 0; i < 8; ++i) a0[i] = (float)v[i];
    }
    for (int base = e0; base < end; base += 64) {
        int ce = base + lane;
        int cidx = (ce < end) ? col[ce] : 0;
        int m = min(64, end - base);
        int nf = m >> 2;                            // full groups of 4 edges
        int g = 0;
        for (; g + 2 <= nf; g += 2) {
            int s0 = __shfl(cidx, 4 * g + q);
            int s1 = __shfl(cidx, 4 * g + 4 + q);
            half8 v0 = t8[(size_t)s0 * 16 + l16];
            half8 v1 = t8[(size_t)s1 * 16 + l16];
            #pragma unroll
            for (int i = 0; i < 8; ++i) {
                a0[i] += (float)v0[i];
                a1[i] += (float)v1[i];
            }
        }
        if (g < nf) {
            int s0 = __shfl(cidx, 4 * g + q);
            half8 v0 = t8[(size_t)s0 * 16 + l16];
            #pragma unroll
            for (int i = 0; i < 8; ++i) a0[i] += (float)v0[i];
        }
        int tail = m & 3;
        if (tail) {
            int s = __shfl(cidx, 4 * nf + q);       // all lanes active here
            if (q < tail) {
                half8 v = t8[(size_t)s * 16 + l16];
                #pragma unroll
                for (int i = 0; i < 8; ++i) a0[i] += (float)v[i];
            }
        }
    }
    #pragma unroll
    for (int i = 0; i < 8; ++i) {
        float t = a0[i] + a1[i];
        t += __shfl_xor(t, 16);
        t += __shfl_xor(t, 32);
        acc[i] = t;
    }
}

// gather layer 1: out[n] (fp32) = relu(dinv[n]*(tS[n] + sum in-edges) + b)
__global__ __launch_bounds__(256) void k_gather1(const _Float16* __restrict__ tS,
                                                 const int* __restrict__ rowptr,
                                                 const int* __restrict__ col,
                                                 const float* __restrict__ dinv,
                                                 const float* __restrict__ b,
                                                 float* __restrict__ out, int n) {
    int node = blockIdx.x * 4 + (threadIdx.x >> 6);
    int lane = threadIdx.x & 63;
    int q = lane >> 4, l16 = lane & 15;
    if (node >= n) return;
    int e0 = rowptr[node], end = rowptr[node + 1];
    float acc[8];
    gather_rows_h((const half8*)tS, col, node, e0, end, acc);
    if (q == 0) {
        float dn = dinv[node];
        const float4* b4 = (const float4*)b;
        float4 bb0 = b4[2 * l16], bb1 = b4[2 * l16 + 1];
        float4 r0, r1;
        r0.x = fmaxf(dn * acc[0] + bb0.x, 0.0f);
        r0.y = fmaxf(dn * acc[1] + bb0.y, 0.0f);
        r0.z = fmaxf(dn * acc[2] + bb0.z, 0.0f);
        r0.w = fmaxf(dn * acc[3] + bb0.w, 0.0f);
        r1.x = fmaxf(dn * acc[4] + bb1.x, 0.0f);
        r1.y = fmaxf(dn * acc[5] + bb1.y, 0.0f);
        r1.z = fmaxf(dn * acc[6] + bb1.z, 0.0f);
        r1.w = fmaxf(dn * acc[7] + bb1.w, 0.0f);
        float4* o = (float4*)(out + (size_t)node * H + l16 * 8);
        o[0] = r0;
        o[1] = r1;
    }
}

// gather layer 2 fused with pool head: v = relu(...); pool[batch[n]] += dot(v, Wp)
__global__ __launch_bounds__(256) void k_gather2(const _Float16* __restrict__ tS,
                                                 const int* __restrict__ rowptr,
                                                 const int* __restrict__ col,
                                                 const float* __restrict__ dinv,
                                                 const float* __restrict__ b,
                                                 const float* __restrict__ Wp,
                                                 const int* __restrict__ batch,
                                                 float* __restrict__ pool,
                                                 float* __restrict__ cnt, int n) {
    int node = blockIdx.x * 4 + (threadIdx.x >> 6);
    int lane = threadIdx.x & 63;
    int l16 = lane & 15;
    if (node >= n) return;
    int e0 = rowptr[node], end = rowptr[node + 1];
    float acc[8];
    gather_rows_h((const half8*)tS, col, node, e0, end, acc);
    float dn = dinv[node];
    const float4* b4 = (const float4*)b;
    const float4* w4 = (const float4*)Wp;
    float4 bb0 = b4[2 * l16], bb1 = b4[2 * l16 + 1];
    float4 wp0 = w4[2 * l16], wp1 = w4[2 * l16 + 1];
    float s = fmaxf(dn * acc[0] + bb0.x, 0.0f) * wp0.x +
              fmaxf(dn * acc[1] + bb0.y, 0.0f) * wp0.y +
              fmaxf(dn * acc[2] + bb0.z, 0.0f) * wp0.z +
              fmaxf(dn * acc[3] + bb0.w, 0.0f) * wp0.w +
              fmaxf(dn * acc[4] + bb1.x, 0.0f) * wp1.x +
              fmaxf(dn * acc[5] + bb1.y, 0.0f) * wp1.y +
              fmaxf(dn * acc[6] + bb1.z, 0.0f) * wp1.z +
              fmaxf(dn * acc[7] + bb1.w, 0.0f) * wp1.w;
    // all quarters hold identical partials per l16; reduce over l16
    s += __shfl_xor(s, 1);
    s += __shfl_xor(s, 2);
    s += __shfl_xor(s, 4);
    s += __shfl_xor(s, 8);
    if (lane == 0) {
        int g = batch[node];
        atomicAdd(&pool[g], s);
        atomicAdd(&cnt[g], 1.0f);
    }
}

// ---------------------------------------------------------------------------
__global__ __launch_bounds__(256) void final_out_kernel(const float* __restrict__ pool,
                                                        const float* __restrict__ cnt,
                                                        const float* __restrict__ bp,
                                                        float* __restrict__ out, int g) {
    int i = blockIdx.x * 256 + threadIdx.x;
    if (i < g) out[i] = pool[i] / fmaxf(cnt[i], 1.0f) + bp[0];
}

// ---------------------------------------------------------------------------
extern "C" void kernel_launch(void* const* d_in, const int* in_sizes, int n_in,
                              void* d_out, int out_size, void* d_ws, size_t ws_size,
                              hipStream_t stream) {
    const float* x     = (const float*)d_in[0];
    const int*   ei    = (const int*)d_in[1];   // [2, E]: src = ei[0:E], dst = ei[E:2E]
    const int*   batch = (const int*)d_in[2];
    const float* W1    = (const float*)d_in[3];
    const float* b1    = (const float*)d_in[4];
    const float* W2    = (const float*)d_in[5];
    const float* b2    = (const float*)d_in[6];
    const float* Wp    = (const float*)d_in[7];
    const float* bp    = (const float*)d_in[8];
    float* out = (float*)d_out;

    const int E = in_sizes[1] / 2;   // 1,600,000
    const int* src = ei;
    const int* dst = ei + E;

    // workspace layout (aligned chunks)
    const size_t BUFH = (size_t)NN * H * sizeof(_Float16);   // 25.6 MB (fp16 msgs)
    const size_t BUFF = (size_t)NN * H * sizeof(float);      // 51.2 MB (fp32 h1)
    const size_t NI  = 401408;                                // >= (NN+1)*4, 4KB-mult
    char* ws = (char*)d_ws;
    size_t off = 0;
    _Float16* tS  = (_Float16*)(ws + off); off += BUFH;      // GEMM outputs (fp16)
    float* h1     = (float*)(ws + off); off += BUFF;         // layer-1 activations
    int*   deg    = (int*)  (ws + off); off += NI;
    int*   rowptr = (int*)  (ws + off); off += NI;
    int*   cursor = (int*)  (ws + off); off += NI;
    float* dinv   = (float*)(ws + off); off += NI;
    int*   col    = (int*)  (ws + off); off += ((size_t)E * 4 + 4095) / 4096 * 4096;
    int*   bsum   = (int*)  (ws + off); off += 4096;
    float* pool   = (float*)(ws + off); off += 2048;
    float* cnt    = (float*)(ws + off); off += 2048;

    const int NB = (NN + 255) / 256;   // 391 scan blocks

    // --- CSR build + degree norm ---
    hipMemsetAsync(deg, 0, NN * sizeof(int), stream);
    hipMemsetAsync(pool, 0, 4096, stream);                   // pool + cnt
    k_hist<<<(E + 255) / 256, 256, 0, stream>>>(dst, deg, E);
    k_scan_block<<<NB, 256, 0, stream>>>(deg, rowptr, bsum, NN);
    k_scan_top<<<1, 512, 0, stream>>>(bsum, NB);
    k_scan_fin<<<NB, 256, 0, stream>>>(rowptr, bsum, deg, cursor, dinv, NN, E);
    k_fill<<<(E + 255) / 256, 256, 0, stream>>>(src, dst, cursor, col, E);

    // --- layer 1 ---
    gemm128h<<<NN / 32, 256, 0, stream>>>(x, W1, dinv, tS);
    k_gather1<<<(NN + 3) / 4, 256, 0, stream>>>(tS, rowptr, col, dinv, b1, h1, NN);

    // --- layer 2 ---
    gemm128h<<<NN / 32, 256, 0, stream>>>(h1, W2, dinv, tS);
    k_gather2<<<(NN + 3) / 4, 256, 0, stream>>>(tS, rowptr, col, dinv, b2, Wp,
                                                batch, pool, cnt, NN);

    // --- head ---
    final_out_kernel<<<(NG + 255) / 256, 256, 0, stream>>>(pool, cnt, bp, out, NG);
}